// Round 1
// baseline (91.527 us; speedup 1.0000x reference)
//
#include <hip/hip_runtime.h>
#include <hip/hip_bf16.h>

// Problem constants
#define B_ 2
#define C_ 256
#define O_ 256
#define T_ 16
#define H_ 64
#define W_ 64

typedef __bf16 bf16x8 __attribute__((ext_vector_type(8)));
typedef float  f32x4  __attribute__((ext_vector_type(4)));

// ws layout:
//   [0, 131072)       : W3d bf16 pre-swizzled LDS image: [mt(2)][kk(4)][8192 elems]
//   [131072, 163840)  : obj f32 [b][o][t]  (B*O*T = 8192 floats)
#define WS_OBJ_OFF 131072

__device__ __forceinline__ void gload_lds16(const void* g, void* l) {
    __builtin_amdgcn_global_load_lds(
        (const __attribute__((address_space(1))) void*)g,
        (__attribute__((address_space(3))) void*)l, 16, 0, 0);
}

// ---------------- prep kernel ----------------
// blocks 0..31  : obj[b,o,t] = sum_c W1d[o,c]*fea_obj[b,c,t] + b1d[o]
// blocks 32..63 : W3d -> bf16 pre-swizzled image in ws
__global__ __launch_bounds__(256) void prep_kernel(
    const float* __restrict__ fea_obj, const float* __restrict__ W3d,
    const float* __restrict__ W1d, const float* __restrict__ b1d,
    __bf16* __restrict__ wsA, float* __restrict__ wsObj) {
    const int bid = blockIdx.x;
    const int tid = threadIdx.x;
    if (bid < 32) {
        const int b = bid >> 4, t = bid & 15;
        __shared__ float fo[C_];
        fo[tid] = fea_obj[(b * C_ + tid) * T_ + t];
        __syncthreads();
        const int o = tid;
        const float4* wrow = (const float4*)(W1d + o * C_);
        float s = 0.f;
#pragma unroll 8
        for (int cq = 0; cq < C_ / 4; ++cq) {
            float4 wv = wrow[cq];
            s += wv.x * fo[cq * 4 + 0] + wv.y * fo[cq * 4 + 1] +
                 wv.z * fo[cq * 4 + 2] + wv.w * fo[cq * 4 + 3];
        }
        wsObj[(b * O_ + o) * T_ + t] = s + b1d[o];
    } else {
        // 8192 groups of 8 consecutive c
        const int g = (bid - 32) * 256 + tid;
        const int o = g >> 5;        // 0..255
        const int cg = g & 31;       // group of 8 c's
        const float* sp = W3d + o * C_ + cg * 8;
        float4 a0 = *(const float4*)sp;
        float4 a1 = *(const float4*)(sp + 4);
        bf16x8 pk;
        pk[0] = (__bf16)a0.x; pk[1] = (__bf16)a0.y;
        pk[2] = (__bf16)a0.z; pk[3] = (__bf16)a0.w;
        pk[4] = (__bf16)a1.x; pk[5] = (__bf16)a1.y;
        pk[6] = (__bf16)a1.z; pk[7] = (__bf16)a1.w;
        const int mt = o >> 7, o_l = o & 127;
        const int kk = cg >> 3, cgl = cg & 7;
        const int dstb = (mt * 4 + kk) * 16384 + o_l * 128 +
                         ((cgl * 16) ^ ((o_l & 7) << 4));
        *(bf16x8*)((char*)wsA + dstb) = pk;
    }
}

// ---------------- main kernel ----------------
// One block per (mt, h, b, t): BM=128 (o), BN=64 (w), K=256 (c), BK=64.
// 4 waves in 2x2; each wave computes 64x32 via 4x2 frags of 16x16.
__global__ __launch_bounds__(256) void main_kernel(
    const float* __restrict__ fea_th, const float* __restrict__ fea_tw,
    const float* __restrict__ heatmap, const float* __restrict__ mask,
    const float* __restrict__ b3d,
    const __bf16* __restrict__ wsA, const float* __restrict__ wsObj,
    float* __restrict__ out) {
    const int tid  = threadIdx.x;
    const int lane = tid & 63;
    const int wv   = tid >> 6;       // 0..3
    const int wv_m = wv >> 1;        // 0..1 -> o offset *64
    const int wv_n = wv & 1;         // 0..1 -> w offset *32

    const int bid = blockIdx.x;      // 4096 blocks
    const int mt  = bid & 1;
    const int h   = (bid >> 1) & 63;
    const int bt  = bid >> 7;        // 0..31
    const int b   = bt >> 4, t = bt & 15;

    __shared__ __align__(16) char smem[16384 + 8192];
    char* sA = smem;            // A tile: [128 o][64 c] bf16, rows 128B, XOR-swizzled
    char* sB = smem + 16384;    // Zt tile: [64 w][64 c] bf16, rows 128B, XOR-swizzled

    f32x4 acc[4][2] = {};

    // B staging setup: thread -> (w = tid&63, cg in {wv, wv+4})
    const int w_s = tid & 63;
    const float* tw_base = fea_tw + ((b * C_) * T_ + t) * W_ + w_s;  // + c*T_*W_
    const float* th_base = fea_th + ((b * C_) * T_ + t) * H_ + h;    // + c*T_*H_
    const __bf16* wsA_tile = wsA + mt * 4 * 8192;

    const int swz = (lane & 7) << 4;
    const int kgrp = lane >> 4;

    for (int kk = 0; kk < 4; ++kk) {
        if (kk) __syncthreads();   // previous compute done before LDS overwrite

        // ---- stage A: 16 KiB via global_load_lds (pre-swizzled image) ----
#pragma unroll
        for (int q = 0; q < 4; ++q) {
            const int chunk = q * 4 + wv;
            gload_lds16(wsA_tile + kk * 8192 + chunk * 512 + lane * 8,
                        sA + chunk * 1024);
        }

        // ---- stage B: Zt[w][c] = th[c,h]*tw[c,w] -> bf16 ----
#pragma unroll
        for (int i = 0; i < 2; ++i) {
            const int cg = wv + i * 4;          // 0..7
            const int cbase = kk * 64 + cg * 8; // global c
            bf16x8 pk;
#pragma unroll
            for (int j = 0; j < 8; ++j) {
                float twv = tw_base[(cbase + j) * (T_ * W_)];
                float thv = th_base[(cbase + j) * (T_ * H_)];
                pk[j] = (__bf16)(twv * thv);
            }
            const int off = w_s * 128 + ((cg * 16) ^ ((w_s & 7) << 4));
            *(bf16x8*)(sB + off) = pk;
        }

        __syncthreads();  // drains vmcnt (gll) + lgkmcnt (ds_write)

        // ---- compute: 2 k-steps of 16x16x32 ----
#pragma unroll
        for (int ks = 0; ks < 2; ++ks) {
            const int kbyte = ks * 64 + kgrp * 16;
            bf16x8 af[4], bfr[2];
#pragma unroll
            for (int m = 0; m < 4; ++m) {
                const int row = wv_m * 64 + m * 16 + (lane & 15);
                af[m] = *(const bf16x8*)(sA + row * 128 + (kbyte ^ swz));
            }
#pragma unroll
            for (int n = 0; n < 2; ++n) {
                const int row = wv_n * 32 + n * 16 + (lane & 15);
                bfr[n] = *(const bf16x8*)(sB + row * 128 + (kbyte ^ swz));
            }
#pragma unroll
            for (int m = 0; m < 4; ++m)
#pragma unroll
                for (int n = 0; n < 2; ++n)
                    acc[m][n] = __builtin_amdgcn_mfma_f32_16x16x32_bf16(
                        af[m], bfr[n], acc[m][n], 0, 0, 0);
        }
    }

    // ---- epilogue: bias + heatmap blend + mask + store ----
    const int colbase = wv_n * 32 + (lane & 15);
    const int obase   = mt * 128 + wv_m * 64 + (lane >> 4) * 4;
    const int hm_base = (b * T_ + t) * (H_ * W_) + h * W_;

    float ht[2], mk[2];
#pragma unroll
    for (int n = 0; n < 2; ++n) {
        const int wcol = colbase + n * 16;
        ht[n] = heatmap[hm_base + wcol];
        mk[n] = mask[hm_base + wcol];
    }

#pragma unroll
    for (int m = 0; m < 4; ++m) {
#pragma unroll
        for (int reg = 0; reg < 4; ++reg) {
            const int o = obase + m * 16 + reg;
            const float bias = b3d[o];
            const float ob   = wsObj[(b * O_ + o) * T_ + t];
            float* orow = out + (((size_t)(b * O_ + o) * T_ + t) * H_ + h) * W_;
#pragma unroll
            for (int n = 0; n < 2; ++n) {
                float v = acc[m][n][reg] + bias;
                v = v * (1.f - ht[n]) + ob * ht[n];
                v *= mk[n];
                orow[colbase + n * 16] = v;
                (void)0;
            }
        }
    }
}

extern "C" void kernel_launch(void* const* d_in, const int* in_sizes, int n_in,
                              void* d_out, int out_size, void* d_ws, size_t ws_size,
                              hipStream_t stream) {
    const float* fea_th  = (const float*)d_in[0];
    const float* fea_tw  = (const float*)d_in[1];
    const float* fea_obj = (const float*)d_in[2];
    const float* heatmap = (const float*)d_in[3];
    const float* mask    = (const float*)d_in[4];
    const float* W3d     = (const float*)d_in[5];
    const float* b3d     = (const float*)d_in[6];
    const float* W1d     = (const float*)d_in[7];
    const float* b1d     = (const float*)d_in[8];
    float* out = (float*)d_out;

    __bf16* wsA  = (__bf16*)d_ws;
    float* wsObj = (float*)((char*)d_ws + WS_OBJ_OFF);

    hipLaunchKernelGGL(prep_kernel, dim3(64), dim3(256), 0, stream,
                       fea_obj, W3d, W1d, b1d, wsA, wsObj);
    hipLaunchKernelGGL(main_kernel, dim3(4096), dim3(256), 0, stream,
                       fea_th, fea_tw, heatmap, mask, b3d, wsA, wsObj, out);
}